// Round 3
// baseline (135.568 us; speedup 1.0000x reference)
//
#include <hip/hip_runtime.h>

// Multi-scale gradient-difference loss as line-parallel reductions.
// Lane owns center position (registers), taps via 2x ds_read_b128 from an
// AoS float4x2 LDS line (zero-padded), per-block f64 atomics.
// R3 fix: cap scale count at NSCALES (s <= 199, MAX_SCALE_CAP) — R2 ran
// geometric scales up to 253 on long lines, inflating sums ~1.7%.

#define NSCALES 67
#define IMG_H 256
#define IMG_W 256
#define NPIX 65536
#define NLINES 2046          // 512 rows (H) + 512 cols (V) + 1022 diagonals (D)
#define LMAX_PAD 320         // 256 positions + 64 zero pad (tap reach <= L+62 <= 318)

// ws layout (doubles):
//  [0..3]  b0: {S1, S2, posCnt, sumAbsPrd}
//  [4..7]  b1: same
//  [8..9]  roiSum[b]
//  [16..17] c[b]   [18..19] invC[b]   [20..21] term2+term3[b]
//  [24..25] T1 partial[b]

__device__ __forceinline__ double wave_red(double v) {
#pragma unroll
  for (int o = 32; o > 0; o >>= 1) v += __shfl_down(v, o, 64);
  return v;
}

// line id -> (batch, flat base index, stride, length)
__device__ __forceinline__ void decode_line(int id, int& b, int& base, int& stride, int& L) {
  if (id < 512) {                      // horizontal row
    b = id >> 8; int y = id & 255;
    base = y * IMG_W; stride = 1; L = IMG_W;
  } else if (id < 1024) {              // vertical column
    int t = id - 512; b = t >> 8;
    base = t & 255; stride = IMG_W; L = IMG_H;
  } else {                             // diagonal c = x - y in [-255,255]
    int t = id - 1024; b = (t >= 511) ? 1 : 0;
    int d = t - b * 511; int c = d - 255;
    int ac = (c < 0) ? -c : c;
    base = (c < 0) ? (-c) * IMG_W : c;
    stride = IMG_W + 1; L = 256 - ac;
  }
}

// #scales this wave must run: s = 1+3k <= min(rem, 199)
__device__ __forceinline__ int scale_count(int L, int wid) {
  int rem = L - 1 - (wid << 6);
  int kcnt = (rem >= 1) ? ((rem - 1) / 3 + 1) : 0;
  return (kcnt > NSCALES) ? NSCALES : kcnt;
}

// Stage one line into AoS LDS; returns center values in regs via refs.
__device__ __forceinline__ void stage_line(
    const float* __restrict__ Pred, const float* __restrict__ GT,
    const float* __restrict__ ROI, int b, int base, int stride, int L,
    int tid, float4 (&buf)[LMAX_PAD][2],
    float& cr, float& cp0, float& cp1, float& cp2,
    float& cg0, float& cg1, float& cg2) {
  const float* P = Pred + b * (3 * NPIX);
  const float* G = GT + b * (3 * NPIX);
  const float* R = ROI + b * NPIX;
  cr = 0.f; cp0 = 0.f; cp1 = 0.f; cp2 = 0.f; cg0 = 0.f; cg1 = 0.f; cg2 = 0.f;
  if (tid < L) {
    int a = base + tid * stride;
    cr = R[a];
    cp0 = P[a]; cp1 = P[a + NPIX]; cp2 = P[a + 2 * NPIX];
    cg0 = G[a]; cg1 = G[a + NPIX]; cg2 = G[a + 2 * NPIX];
  }
  buf[tid][0] = make_float4(cr, cp0, cp1, cp2);
  buf[tid][1] = make_float4(cg0, cg1, cg2, 0.f);
  if (tid < LMAX_PAD - 256) {
    buf[256 + tid][0] = make_float4(0.f, 0.f, 0.f, 0.f);
    buf[256 + tid][1] = make_float4(0.f, 0.f, 0.f, 0.f);
  }
  __syncthreads();
}

extern "C" __global__ void __launch_bounds__(256, 4) pass1_kernel(
    const float* __restrict__ Pred, const float* __restrict__ GT,
    const float* __restrict__ ROI, double* __restrict__ ws) {
  __shared__ float4 buf[LMAX_PAD][2];
  __shared__ double red[4][5];
  const int id = blockIdx.x;
  const int tid = threadIdx.x;
  const int wid = tid >> 6, lane = tid & 63;

  int b, base, stride, L;
  decode_line(id, b, base, stride, L);
  float cr, cp0, cp1, cp2, cg0, cg1, cg2;
  stage_line(Pred, GT, ROI, b, base, stride, L, tid, buf,
             cr, cp0, cp1, cp2, cg0, cg1, cg2);

  const int kcnt = scale_count(L, wid);

  float f1 = 0.f, f2 = 0.f, fp = 0.f;
  int pci = 0;
  const float* bp = (const float*)&buf[tid + 1][0];   // tap pointer, s=1
  for (int k = 0; k < kcnt; ++k) {
    float4 t0 = ((const float4*)bp)[0];
    float4 t1 = ((const float4*)bp)[1];
    bp += 24;                                         // s += 3 (8 floats/pos)
    float rr = cr * t0.x;
#define L1BODY(cp, cg, tp, tg)                                   \
    {                                                            \
      float dP = rr * (cp - tp);                                 \
      float dG = rr * (cg - tg);                                 \
      float q = dP * __builtin_amdgcn_rcpf(dG + 1e-5f);          \
      float aG = fabsf(dG);                                      \
      f1 += fmaxf(aG * q, 0.f);                                  \
      if (q > 0.f) f2 += aG;                                     \
      if (dG > 0.f) pci++;                                       \
      fp += fabsf(dP);                                           \
    }
    L1BODY(cp0, cg0, t0.y, t1.x)
    L1BODY(cp1, cg1, t0.z, t1.y)
    L1BODY(cp2, cg2, t0.w, t1.z)
#undef L1BODY
  }

  double w0 = wave_red((double)f1);
  double w1 = wave_red((double)f2);
  double w2 = wave_red((double)pci);
  double w3 = wave_red((double)fp);
  double w4 = wave_red((double)cr);                   // ROI partial (H rows only)
  if (lane == 0) {
    red[wid][0] = w0; red[wid][1] = w1; red[wid][2] = w2;
    red[wid][3] = w3; red[wid][4] = w4;
  }
  __syncthreads();
  if (tid < 4)
    unsafeAtomicAdd(&ws[b * 4 + tid],
                    red[0][tid] + red[1][tid] + red[2][tid] + red[3][tid]);
  if (tid == 4 && id < 512)                           // H rows tile ROI exactly once
    unsafeAtomicAdd(&ws[8 + b], red[0][4] + red[1][4] + red[2][4] + red[3][4]);
}

extern "C" __global__ void __launch_bounds__(64) mid_kernel(
    double* __restrict__ ws, float* __restrict__ out) {
  if (threadIdx.x == 0) {
    for (int b = 0; b < 2; ++b) {
      double S1 = ws[b * 4 + 0], S2 = ws[b * 4 + 1];
      double PC = ws[b * 4 + 2], SP = ws[b * 4 + 3];
      double RS = ws[8 + b];
      float c = (float)(S1 / (S2 + 1e-4));
      out[1 + b] = c;                                 // NormConst
      float meanPrd = (float)(SP / PC);
      bool big = RS > 200.0;
      float term2 = (big && meanPrd > 30.f && c > 10.f) ? (meanPrd - 30.f) : 0.f;
      float fact = 0.1f / (c + 0.001f);
      float term3 = (big && meanPrd < 2.f && c < 0.1f) ? (0.2f - meanPrd) * fact : 0.f;
      ws[16 + b] = (double)c;
      ws[18 + b] = (c > 1e-4f) ? (1.0 / (double)c) : 1.0;
      ws[20 + b] = (double)(term2 + term3);
      ws[24 + b] = 0.0;                               // T1 accumulators
    }
  }
}

extern "C" __global__ void __launch_bounds__(256, 4) pass2_kernel(
    const float* __restrict__ Pred, const float* __restrict__ GT,
    const float* __restrict__ ROI, double* __restrict__ ws) {
  __shared__ float4 buf[LMAX_PAD][2];
  __shared__ double red[4];
  const int id = blockIdx.x;
  const int tid = threadIdx.x;
  const int wid = tid >> 6, lane = tid & 63;

  int b, base, stride, L;
  decode_line(id, b, base, stride, L);
  const float invC = (float)ws[18 + b];
  float cr, cp0, cp1, cp2, cg0, cg1, cg2;
  stage_line(Pred, GT, ROI, b, base, stride, L, tid, buf,
             cr, cp0, cp1, cp2, cg0, cg1, cg2);

  const int kcnt = scale_count(L, wid);

  float f = 0.f;
  const float* bp = (const float*)&buf[tid + 1][0];
  for (int k = 0; k < kcnt; ++k) {
    float4 t0 = ((const float4*)bp)[0];
    float4 t1 = ((const float4*)bp)[1];
    bp += 24;
    float rr = cr * t0.x;
    // |difGT - difPrd*invC| = rr * |(g-gt) - (p-pt)*invC|   (rr in {0,1})
    f += rr * fabsf((cg0 - t1.x) - (cp0 - t0.y) * invC);
    f += rr * fabsf((cg1 - t1.y) - (cp1 - t0.z) * invC);
    f += rr * fabsf((cg2 - t1.z) - (cp2 - t0.w) * invC);
  }
  double t = wave_red((double)f);
  if (lane == 0) red[wid] = t;
  __syncthreads();
  if (tid == 0)
    unsafeAtomicAdd(&ws[24 + b], red[0] + red[1] + red[2] + red[3]);
}

extern "C" __global__ void __launch_bounds__(64) final_kernel(
    const double* __restrict__ ws, float* __restrict__ out) {
  if (threadIdx.x == 0) {
    double loss = 0.0;
    for (int b = 0; b < 2; ++b) {
      double c = ws[16 + b];
      double term1 = (c > 1e-4) ? ws[24 + b] / (603.0 * 65536.0) : 0.0;
      loss += term1 + ws[20 + b];
    }
    out[0] = (float)loss;
  }
}

extern "C" void kernel_launch(void* const* d_in, const int* in_sizes, int n_in,
                              void* d_out, int out_size, void* d_ws, size_t ws_size,
                              hipStream_t stream) {
  (void)in_sizes; (void)n_in; (void)out_size; (void)ws_size;
  const float* Pred = (const float*)d_in[0];
  const float* GT = (const float*)d_in[1];
  const float* ROI = (const float*)d_in[2];
  float* out = (float*)d_out;
  double* ws = (double*)d_ws;

  hipMemsetAsync(d_ws, 0, 32 * sizeof(double), stream);   // zero accumulators
  hipLaunchKernelGGL(pass1_kernel, dim3(NLINES), dim3(256), 0, stream,
                     Pred, GT, ROI, ws);
  hipLaunchKernelGGL(mid_kernel, dim3(1), dim3(64), 0, stream, ws, out);
  hipLaunchKernelGGL(pass2_kernel, dim3(NLINES), dim3(256), 0, stream,
                     Pred, GT, ROI, ws);
  hipLaunchKernelGGL(final_kernel, dim3(1), dim3(64), 0, stream, ws, out);
}

// Round 5
// 131.284 us; speedup vs baseline: 1.0326x; 1.0326x over previous
//
#include <hip/hip_runtime.h>

// Multi-scale gradient-difference loss as line-parallel reductions.
// R5: rollback to multi-kernel dataflow (kernel boundaries give cross-XCD
// coherence for the ws handoff — the R4 cooperative fusion corrupted T1),
// keeping two proven-safe intra-kernel wins:
//   - split dense float4 LDS buffers -> conflict-free ds_read_b128
//   - heavy-scale wave role rotated by blockIdx -> SIMD load balance
// mid_kernel dropped: pass2 computes invC inline; final computes term2/3.

#define NSCALES 67
#define IMG_H 256
#define IMG_W 256
#define NPIX 65536
#define NLINES 2046          // 512 rows (H) + 512 cols (V) + 1022 diagonals (D)
#define LMAX_PAD 320         // 256 positions + 64 zero pad (max tap index 318)

// ws layout (doubles):
//  [0..3] b0 {S1,S2,posCnt,sumAbsPrd}  [4..7] b1 same
//  [8..9] roiSum[b]   [24..25] T1[b]

__device__ __forceinline__ double wave_red(double v) {
#pragma unroll
  for (int o = 32; o > 0; o >>= 1) v += __shfl_down(v, o, 64);
  return v;
}

__device__ __forceinline__ void decode_line(int id, int& b, int& base, int& stride, int& L) {
  if (id < 512) {                      // horizontal row
    b = id >> 8; int y = id & 255;
    base = y * IMG_W; stride = 1; L = IMG_W;
  } else if (id < 1024) {              // vertical column
    int t = id - 512; b = t >> 8;
    base = t & 255; stride = IMG_W; L = IMG_H;
  } else {                             // diagonal c = x - y in [-255,255]
    int t = id - 1024; b = (t >= 511) ? 1 : 0;
    int d = t - b * 511; int c = d - 255;
    int ac = (c < 0) ? -c : c;
    base = (c < 0) ? (-c) * IMG_W : c;
    stride = IMG_W + 1; L = 256 - ac;
  }
}

// #scales for the wave owning centers [role*64, role*64+63]: s = 1+3k <= min(rem,199)
__device__ __forceinline__ int scale_count(int L, int role) {
  int rem = L - 1 - (role << 6);
  int kcnt = (rem >= 1) ? ((rem - 1) / 3 + 1) : 0;
  return (kcnt > NSCALES) ? NSCALES : kcnt;
}

__device__ __forceinline__ void stage_line(
    const float* __restrict__ Pred, const float* __restrict__ GT,
    const float* __restrict__ ROI, int b, int base, int stride, int L,
    int tid, float4* bufA, float4* bufB) {
  const float* P = Pred + b * (3 * NPIX);
  const float* G = GT + b * (3 * NPIX);
  const float* R = ROI + b * NPIX;
  float r = 0.f, p0 = 0.f, p1 = 0.f, p2 = 0.f, g0 = 0.f, g1 = 0.f, g2 = 0.f;
  if (tid < L) {
    int a = base + tid * stride;
    r = R[a];
    p0 = P[a]; p1 = P[a + NPIX]; p2 = P[a + 2 * NPIX];
    g0 = G[a]; g1 = G[a + NPIX]; g2 = G[a + 2 * NPIX];
  }
  bufA[tid] = make_float4(r, p0, p1, p2);
  bufB[tid] = make_float4(g0, g1, g2, 0.f);
  if (tid < LMAX_PAD - 256) {
    bufA[256 + tid] = make_float4(0.f, 0.f, 0.f, 0.f);
    bufB[256 + tid] = make_float4(0.f, 0.f, 0.f, 0.f);
  }
  __syncthreads();
}

extern "C" __global__ void __launch_bounds__(256, 8) pass1_kernel(
    const float* __restrict__ Pred, const float* __restrict__ GT,
    const float* __restrict__ ROI, double* __restrict__ ws) {
  __shared__ float4 bufA[LMAX_PAD];    // {r, p0, p1, p2}
  __shared__ float4 bufB[LMAX_PAD];    // {g0, g1, g2, 0}
  __shared__ double red[4][5];
  const int id = blockIdx.x;
  const int tid = threadIdx.x;
  const int wid = tid >> 6, lane = tid & 63;
  const int role = (wid + id) & 3;             // rotate heavy scale range
  const int c = (role << 6) + lane;            // this lane's center position

  int b, base, stride, L;
  decode_line(id, b, base, stride, L);
  stage_line(Pred, GT, ROI, b, base, stride, L, tid, bufA, bufB);

  const float4 cA = bufA[c];
  const float4 cB = bufB[c];
  const float cr = cA.x, cp0 = cA.y, cp1 = cA.z, cp2 = cA.w;
  const float cg0 = cB.x, cg1 = cB.y, cg2 = cB.z;

  const int kcnt = scale_count(L, role);

  float f1 = 0.f, f2 = 0.f, fp = 0.f;
  int pci = 0;
  const float4* tA = &bufA[c + 1];
  const float4* tB = &bufB[c + 1];
#pragma unroll 2
  for (int k = 0; k < kcnt; ++k) {
    float4 t0 = tA[0];
    float4 t1 = tB[0];
    tA += 3; tB += 3;                          // s += 3
    float rr = cr * t0.x;
#define L1BODY(cp, cg, tp, tg)                                   \
    {                                                            \
      float dP = rr * (cp - tp);                                 \
      float dG = rr * (cg - tg);                                 \
      float q = dP * __builtin_amdgcn_rcpf(dG + 1e-5f);          \
      float aG = fabsf(dG);                                      \
      f1 += fmaxf(aG * q, 0.f);                                  \
      if (q > 0.f) f2 += aG;                                     \
      if (dG > 0.f) pci++;                                       \
      fp += fabsf(dP);                                           \
    }
    L1BODY(cp0, cg0, t0.y, t1.x)
    L1BODY(cp1, cg1, t0.z, t1.y)
    L1BODY(cp2, cg2, t0.w, t1.z)
#undef L1BODY
  }

  double w0 = wave_red((double)f1);
  double w1 = wave_red((double)f2);
  double w2 = wave_red((double)pci);
  double w3 = wave_red((double)fp);
  double w4 = wave_red((double)cr);            // ROI partial (centers = full line)
  if (lane == 0) {
    red[wid][0] = w0; red[wid][1] = w1; red[wid][2] = w2;
    red[wid][3] = w3; red[wid][4] = w4;
  }
  __syncthreads();
  if (tid < 4)
    unsafeAtomicAdd(&ws[b * 4 + tid],
                    red[0][tid] + red[1][tid] + red[2][tid] + red[3][tid]);
  if (tid == 4 && id < 512)                    // H rows tile ROI exactly once
    unsafeAtomicAdd(&ws[8 + b], red[0][4] + red[1][4] + red[2][4] + red[3][4]);
}

extern "C" __global__ void __launch_bounds__(256, 8) pass2_kernel(
    const float* __restrict__ Pred, const float* __restrict__ GT,
    const float* __restrict__ ROI, double* __restrict__ ws) {
  __shared__ float4 bufA[LMAX_PAD];
  __shared__ float4 bufB[LMAX_PAD];
  __shared__ double red[4];
  __shared__ float s_invC;
  const int id = blockIdx.x;
  const int tid = threadIdx.x;
  const int wid = tid >> 6, lane = tid & 63;
  const int role = (wid + id) & 3;
  const int c = (role << 6) + lane;

  int b, base, stride, L;
  decode_line(id, b, base, stride, L);
  if (tid == 0) {                              // invC from pass1 sums (coherent
    double S1 = ws[b * 4 + 0], S2 = ws[b * 4 + 1];   // across kernel boundary)
    float cc = (float)(S1 / (S2 + 1e-4));
    s_invC = (cc > 1e-4f) ? (float)(1.0 / (double)cc) : 1.0f;
  }
  stage_line(Pred, GT, ROI, b, base, stride, L, tid, bufA, bufB);  // ends in sync

  const float4 cA = bufA[c];
  const float4 cB = bufB[c];
  const float cr = cA.x, cp0 = cA.y, cp1 = cA.z, cp2 = cA.w;
  const float cg0 = cB.x, cg1 = cB.y, cg2 = cB.z;
  const float invC = s_invC;

  const int kcnt = scale_count(L, role);

  float f = 0.f;
  const float4* tA = &bufA[c + 1];
  const float4* tB = &bufB[c + 1];
#pragma unroll 2
  for (int k = 0; k < kcnt; ++k) {
    float4 t0 = tA[0];
    float4 t1 = tB[0];
    tA += 3; tB += 3;
    float rr = cr * t0.x;
    // |difGT - difPrd/c| = rr * |(g-gt) - (p-pt)*invC|   (rr in {0,1})
    f += rr * fabsf((cg0 - t1.x) - (cp0 - t0.y) * invC);
    f += rr * fabsf((cg1 - t1.y) - (cp1 - t0.z) * invC);
    f += rr * fabsf((cg2 - t1.z) - (cp2 - t0.w) * invC);
  }
  double t = wave_red((double)f);
  if (lane == 0) red[wid] = t;
  __syncthreads();
  if (tid == 0)
    unsafeAtomicAdd(&ws[24 + b], red[0] + red[1] + red[2] + red[3]);
}

extern "C" __global__ void __launch_bounds__(64) final_kernel(
    const double* __restrict__ ws, float* __restrict__ out) {
  if (threadIdx.x == 0) {
    double loss = 0.0;
    for (int b = 0; b < 2; ++b) {
      double S1 = ws[b * 4 + 0], S2 = ws[b * 4 + 1];
      double PC = ws[b * 4 + 2], SP = ws[b * 4 + 3];
      double RS = ws[8 + b];
      float cc = (float)(S1 / (S2 + 1e-4));
      out[1 + b] = cc;                         // NormConst
      double term1 = (cc > 1e-4f) ? ws[24 + b] / (603.0 * 65536.0) : 0.0;
      float meanPrd = (float)(SP / PC);
      bool big = RS > 200.0;
      float t2 = (big && meanPrd > 30.f && cc > 10.f) ? (meanPrd - 30.f) : 0.f;
      float fact = 0.1f / (cc + 0.001f);
      float t3 = (big && meanPrd < 2.f && cc < 0.1f) ? (0.2f - meanPrd) * fact : 0.f;
      loss += term1 + (double)(t2 + t3);
    }
    out[0] = (float)loss;
  }
}

extern "C" void kernel_launch(void* const* d_in, const int* in_sizes, int n_in,
                              void* d_out, int out_size, void* d_ws, size_t ws_size,
                              hipStream_t stream) {
  (void)in_sizes; (void)n_in; (void)out_size; (void)ws_size;
  const float* Pred = (const float*)d_in[0];
  const float* GT = (const float*)d_in[1];
  const float* ROI = (const float*)d_in[2];
  float* out = (float*)d_out;
  double* ws = (double*)d_ws;

  hipMemsetAsync(d_ws, 0, 32 * sizeof(double), stream);   // zero accumulators
  hipLaunchKernelGGL(pass1_kernel, dim3(NLINES), dim3(256), 0, stream,
                     Pred, GT, ROI, ws);
  hipLaunchKernelGGL(pass2_kernel, dim3(NLINES), dim3(256), 0, stream,
                     Pred, GT, ROI, ws);
  hipLaunchKernelGGL(final_kernel, dim3(1), dim3(64), 0, stream, ws, out);
}

// Round 7
// 128.345 us; speedup vs baseline: 1.0563x; 1.0229x over previous
//
#include <hip/hip_runtime.h>

// Multi-scale gradient-difference loss as line-parallel reductions.
// R6 resubmit (prior round was an infra failure; source never ran).
// Placement-independent wave load balance: R5's role=(wid+id)&3 rotation
// was defeated by HW block placement (CU gets ids spaced by 8 == 0 mod 4, so
// one SIMD/CU always got the 67-scale role: 536-iter critical path, VALUBusy
// 58%). Now each block's (scale,quarter) task list is dealt round-robin to
// its 4 waves: wave w takes tasks t == w (mod 4) -> ~49 tasks/wave always.

#define NSCALES 67
#define IMG_H 256
#define IMG_W 256
#define NPIX 65536
#define NLINES 2046          // 512 rows (H) + 512 cols (V) + 1022 diagonals (D)
#define LMAX_PAD 320         // 256 positions + 64 zero pad (max tap index 318)

// ws layout (doubles):
//  [0..3] b0 {S1,S2,posCnt,sumAbsPrd}  [4..7] b1 same
//  [8..9] roiSum[b]   [24..25] T1[b]

__device__ __forceinline__ double wave_red(double v) {
#pragma unroll
  for (int o = 32; o > 0; o >>= 1) v += __shfl_down(v, o, 64);
  return v;
}

__device__ __forceinline__ void decode_line(int id, int& b, int& base, int& stride, int& L) {
  if (id < 512) {                      // horizontal row
    b = id >> 8; int y = id & 255;
    base = y * IMG_W; stride = 1; L = IMG_W;
  } else if (id < 1024) {              // vertical column
    int t = id - 512; b = t >> 8;
    base = t & 255; stride = IMG_W; L = IMG_H;
  } else {                             // diagonal c = x - y in [-255,255]
    int t = id - 1024; b = (t >= 511) ? 1 : 0;
    int d = t - b * 511; int c = d - 255;
    int ac = (c < 0) ? -c : c;
    base = (c < 0) ? (-c) * IMG_W : c;
    stride = IMG_W + 1; L = 256 - ac;
  }
}

// #scales valid for quarter q (centers [64q, 64q+63]): s = 1+3k <= min(L-1-64q, 199)
__device__ __forceinline__ int scale_count(int L, int q) {
  int rem = L - 1 - (q << 6);
  int kcnt = (rem >= 1) ? ((rem - 1) / 3 + 1) : 0;
  return (kcnt > NSCALES) ? NSCALES : kcnt;
}

// Stage line; returns this tid's ROI value (position tid) for the ROI sum.
__device__ __forceinline__ float stage_line(
    const float* __restrict__ Pred, const float* __restrict__ GT,
    const float* __restrict__ ROI, int b, int base, int stride, int L,
    int tid, float4* bufA, float4* bufB) {
  const float* P = Pred + b * (3 * NPIX);
  const float* G = GT + b * (3 * NPIX);
  const float* R = ROI + b * NPIX;
  float r = 0.f, p0 = 0.f, p1 = 0.f, p2 = 0.f, g0 = 0.f, g1 = 0.f, g2 = 0.f;
  if (tid < L) {
    int a = base + tid * stride;
    r = R[a];
    p0 = P[a]; p1 = P[a + NPIX]; p2 = P[a + 2 * NPIX];
    g0 = G[a]; g1 = G[a + NPIX]; g2 = G[a + 2 * NPIX];
  }
  bufA[tid] = make_float4(r, p0, p1, p2);
  bufB[tid] = make_float4(g0, g1, g2, 0.f);
  if (tid < LMAX_PAD - 256) {
    bufA[256 + tid] = make_float4(0.f, 0.f, 0.f, 0.f);
    bufB[256 + tid] = make_float4(0.f, 0.f, 0.f, 0.f);
  }
  __syncthreads();
  return r;
}

extern "C" __global__ void __launch_bounds__(256, 8) pass1_kernel(
    const float* __restrict__ Pred, const float* __restrict__ GT,
    const float* __restrict__ ROI, double* __restrict__ ws) {
  __shared__ float4 bufA[LMAX_PAD];    // {r, p0, p1, p2}
  __shared__ float4 bufB[LMAX_PAD];    // {g0, g1, g2, 0}
  __shared__ double red[4][5];
  const int id = blockIdx.x;
  const int tid = threadIdx.x;
  const int wid = tid >> 6, lane = tid & 63;

  int b, base, stride, L;
  decode_line(id, b, base, stride, L);
  float stg_r = stage_line(Pred, GT, ROI, b, base, stride, L, tid, bufA, bufB);

  float f1 = 0.f, f2 = 0.f, fp = 0.f;
  int pci = 0;
  int P = 0;                            // task prefix
  for (int q = 0; q < 4; ++q) {
    const int Kq = scale_count(L, q);
    int k = (wid - P) & 3;              // first task of run q owned by this wave
    if (k < Kq) {
      const int c = (q << 6) + lane;
      const float4 cA = bufA[c];
      const float4 cB = bufB[c];
      const float cr = cA.x, cp0 = cA.y, cp1 = cA.z, cp2 = cA.w;
      const float cg0 = cB.x, cg1 = cB.y, cg2 = cB.z;
      const float4* tA = &bufA[c + 1 + 3 * k];
      const float4* tB = &bufB[c + 1 + 3 * k];
#pragma unroll 2
      for (; k < Kq; k += 4) {
        float4 t0 = tA[0];
        float4 t1 = tB[0];
        tA += 12; tB += 12;             // s += 12
        float rr = cr * t0.x;
#define L1BODY(cp, cg, tp, tg)                                   \
        {                                                        \
          float dP = rr * (cp - tp);                             \
          float dG = rr * (cg - tg);                             \
          float qq = dP * __builtin_amdgcn_rcpf(dG + 1e-5f);     \
          float aG = fabsf(dG);                                  \
          f1 += fmaxf(aG * qq, 0.f);                             \
          if (qq > 0.f) f2 += aG;                                \
          if (dG > 0.f) pci++;                                   \
          fp += fabsf(dP);                                       \
        }
        L1BODY(cp0, cg0, t0.y, t1.x)
        L1BODY(cp1, cg1, t0.z, t1.y)
        L1BODY(cp2, cg2, t0.w, t1.z)
#undef L1BODY
      }
    }
    P += Kq;
  }

  double w0 = wave_red((double)f1);
  double w1 = wave_red((double)f2);
  double w2 = wave_red((double)pci);
  double w3 = wave_red((double)fp);
  double w4 = wave_red((double)stg_r);  // ROI partial: position tid, once/block
  if (lane == 0) {
    red[wid][0] = w0; red[wid][1] = w1; red[wid][2] = w2;
    red[wid][3] = w3; red[wid][4] = w4;
  }
  __syncthreads();
  if (tid < 4)
    unsafeAtomicAdd(&ws[b * 4 + tid],
                    red[0][tid] + red[1][tid] + red[2][tid] + red[3][tid]);
  if (tid == 4 && id < 512)             // H rows tile the image exactly once
    unsafeAtomicAdd(&ws[8 + b], red[0][4] + red[1][4] + red[2][4] + red[3][4]);
}

extern "C" __global__ void __launch_bounds__(256, 8) pass2_kernel(
    const float* __restrict__ Pred, const float* __restrict__ GT,
    const float* __restrict__ ROI, double* __restrict__ ws) {
  __shared__ float4 bufA[LMAX_PAD];
  __shared__ float4 bufB[LMAX_PAD];
  __shared__ double red[4];
  __shared__ float s_invC;
  const int id = blockIdx.x;
  const int tid = threadIdx.x;
  const int wid = tid >> 6, lane = tid & 63;

  int b, base, stride, L;
  decode_line(id, b, base, stride, L);
  if (tid == 0) {                       // invC from pass1 sums (kernel boundary
    double S1 = ws[b * 4 + 0], S2 = ws[b * 4 + 1];   // gives coherence)
    float cc = (float)(S1 / (S2 + 1e-4));
    s_invC = (cc > 1e-4f) ? (float)(1.0 / (double)cc) : 1.0f;
  }
  stage_line(Pred, GT, ROI, b, base, stride, L, tid, bufA, bufB);

  const float invC = s_invC;
  float f = 0.f;
  int P = 0;
  for (int q = 0; q < 4; ++q) {
    const int Kq = scale_count(L, q);
    int k = (wid - P) & 3;
    if (k < Kq) {
      const int c = (q << 6) + lane;
      const float4 cA = bufA[c];
      const float4 cB = bufB[c];
      const float cr = cA.x, cp0 = cA.y, cp1 = cA.z, cp2 = cA.w;
      const float cg0 = cB.x, cg1 = cB.y, cg2 = cB.z;
      const float4* tA = &bufA[c + 1 + 3 * k];
      const float4* tB = &bufB[c + 1 + 3 * k];
#pragma unroll 2
      for (; k < Kq; k += 4) {
        float4 t0 = tA[0];
        float4 t1 = tB[0];
        tA += 12; tB += 12;
        float rr = cr * t0.x;
        // |difGT - difPrd/c| = rr * |(g-gt) - (p-pt)*invC|   (rr in {0,1})
        f += rr * fabsf((cg0 - t1.x) - (cp0 - t0.y) * invC);
        f += rr * fabsf((cg1 - t1.y) - (cp1 - t0.z) * invC);
        f += rr * fabsf((cg2 - t1.z) - (cp2 - t0.w) * invC);
      }
    }
    P += Kq;
  }
  double t = wave_red((double)f);
  if (lane == 0) red[wid] = t;
  __syncthreads();
  if (tid == 0)
    unsafeAtomicAdd(&ws[24 + b], red[0] + red[1] + red[2] + red[3]);
}

extern "C" __global__ void __launch_bounds__(64) final_kernel(
    const double* __restrict__ ws, float* __restrict__ out) {
  if (threadIdx.x == 0) {
    double loss = 0.0;
    for (int b = 0; b < 2; ++b) {
      double S1 = ws[b * 4 + 0], S2 = ws[b * 4 + 1];
      double PC = ws[b * 4 + 2], SP = ws[b * 4 + 3];
      double RS = ws[8 + b];
      float cc = (float)(S1 / (S2 + 1e-4));
      out[1 + b] = cc;                  // NormConst
      double term1 = (cc > 1e-4f) ? ws[24 + b] / (603.0 * 65536.0) : 0.0;
      float meanPrd = (float)(SP / PC);
      bool big = RS > 200.0;
      float t2 = (big && meanPrd > 30.f && cc > 10.f) ? (meanPrd - 30.f) : 0.f;
      float fact = 0.1f / (cc + 0.001f);
      float t3 = (big && meanPrd < 2.f && cc < 0.1f) ? (0.2f - meanPrd) * fact : 0.f;
      loss += term1 + (double)(t2 + t3);
    }
    out[0] = (float)loss;
  }
}

extern "C" void kernel_launch(void* const* d_in, const int* in_sizes, int n_in,
                              void* d_out, int out_size, void* d_ws, size_t ws_size,
                              hipStream_t stream) {
  (void)in_sizes; (void)n_in; (void)out_size; (void)ws_size;
  const float* Pred = (const float*)d_in[0];
  const float* GT = (const float*)d_in[1];
  const float* ROI = (const float*)d_in[2];
  float* out = (float*)d_out;
  double* ws = (double*)d_ws;

  hipMemsetAsync(d_ws, 0, 32 * sizeof(double), stream);   // zero accumulators
  hipLaunchKernelGGL(pass1_kernel, dim3(NLINES), dim3(256), 0, stream,
                     Pred, GT, ROI, ws);
  hipLaunchKernelGGL(pass2_kernel, dim3(NLINES), dim3(256), 0, stream,
                     Pred, GT, ROI, ws);
  hipLaunchKernelGGL(final_kernel, dim3(1), dim3(64), 0, stream, ws, out);
}